// Round 6
// baseline (408.824 us; speedup 1.0000x reference)
//
#include <hip/hip_runtime.h>

// Problem constants
#define B_   2
#define NQ_  8192
#define NK_  8192
#define DIN_ 256
#define DH_  256
#define M_   (B_ * NQ_)   // 16384 flattened rows

typedef _Float16 f16x8 __attribute__((ext_vector_type(8)));
typedef unsigned short u16x8 __attribute__((ext_vector_type(8)));
typedef unsigned short u16x4 __attribute__((ext_vector_type(4)));
typedef unsigned int  u32x4 __attribute__((ext_vector_type(4)));
typedef float f32x16 __attribute__((ext_vector_type(16)));

__device__ __forceinline__ unsigned short f2h(float f) {
    _Float16 h = (_Float16)f;
    return __builtin_bit_cast(unsigned short, h);
}
__device__ __forceinline__ float h2f(unsigned short u) {
    return (float)__builtin_bit_cast(_Float16, u);
}

// ---------------------------------------------------------------------------
// Kernel 1: weight convert + transpose via LDS tile (both sides coalesced).
// wt[mat][n][k] = fp16(W[mat][k][n]).  grid (4,4,3), block 256.
// ---------------------------------------------------------------------------
__global__ void wt_conv(const float* __restrict__ Wq, const float* __restrict__ Wk,
                        const float* __restrict__ Wv, unsigned short* __restrict__ wt) {
    __shared__ float tile[64][65];
    const int mat = blockIdx.z;
    const int k0 = blockIdx.x * 64, n0 = blockIdx.y * 64;
    const float* W = (mat == 0) ? Wq : (mat == 1) ? Wk : Wv;
#pragma unroll
    for (int p = 0; p < 16; ++p) {
        const int idx = p * 256 + threadIdx.x;
        const int r = idx >> 6, c = idx & 63;
        tile[r][c] = W[(k0 + r) * 256 + n0 + c];
    }
    __syncthreads();
#pragma unroll
    for (int p = 0; p < 16; ++p) {
        const int idx = p * 256 + threadIdx.x;
        const int nr = idx >> 6, kc = idx & 63;
        wt[mat * 65536 + (n0 + nr) * 256 + k0 + kc] = f2h(tile[kc][nr]);
    }
}

// ---------------------------------------------------------------------------
// Kernel 2: projections with 1-deep register prefetch on the X row chain.
// ---------------------------------------------------------------------------
__global__ __launch_bounds__(256) void proj(
    const float* __restrict__ xq, const float* __restrict__ xk, const float* __restrict__ xv,
    const float* __restrict__ bq, const float* __restrict__ bk, const float* __restrict__ bv,
    const unsigned short* __restrict__ wt,
    unsigned short* __restrict__ q_emb, unsigned short* __restrict__ k_emb,
    unsigned short* __restrict__ v_emb_t) {
    const int mat = blockIdx.y;
    const float* x    = (mat == 0) ? xq : (mat == 1) ? xk : xv;
    const float* bias = (mat == 0) ? bq : (mat == 1) ? bk : bv;
    const unsigned short* w = wt + mat * 65536;

    const int tid = threadIdx.x;
    const int l = tid & 63, wv = tid >> 6;
    const int pair = wv >> 1, h = wv & 1;
    const int lm = l & 31, lh = l >> 5;
    const int row0 = blockIdx.x * 64;
    const int m = row0 + pair * 32 + lm;

    f32x16 acc[4];
#pragma unroll
    for (int i = 0; i < 4; ++i)
#pragma unroll
        for (int j = 0; j < 16; ++j) acc[i][j] = 0.0f;

    const float4* xrow = (const float4*)(x + (size_t)m * 256 + lh * 8);
    float4 a0 = xrow[0], a1 = xrow[1];
#pragma unroll
    for (int ks = 0; ks < 16; ++ks) {
        float4 n0 = a0, n1 = a1;
        if (ks < 15) { n0 = xrow[(ks + 1) * 4]; n1 = xrow[(ks + 1) * 4 + 1]; }
        u16x8 au;
        au[0] = f2h(a0.x); au[1] = f2h(a0.y); au[2] = f2h(a0.z); au[3] = f2h(a0.w);
        au[4] = f2h(a1.x); au[5] = f2h(a1.y); au[6] = f2h(a1.z); au[7] = f2h(a1.w);
        f16x8 af = __builtin_bit_cast(f16x8, au);
#pragma unroll
        for (int nt = 0; nt < 4; ++nt) {
            f16x8 bfr = *(const f16x8*)(w + (h * 128 + nt * 32 + lm) * 256 + ks * 16 + lh * 8);
            acc[nt] = __builtin_amdgcn_mfma_f32_32x32x16_f16(af, bfr, acc[nt], 0, 0, 0);
        }
        a0 = n0; a1 = n1;
    }

    if (mat < 2) {
        unsigned short* emb = (mat == 0) ? q_emb : k_emb;
#pragma unroll
        for (int nt = 0; nt < 4; ++nt) {
            const int n = h * 128 + nt * 32 + lm;
            const float bsv = bias[n];
#pragma unroll
            for (int r = 0; r < 16; ++r) {
                const int rl = (r & 3) + 8 * (r >> 2) + 4 * lh;
                emb[(size_t)(row0 + pair * 32 + rl) * 256 + n] = f2h(acc[nt][r] + bsv);
            }
        }
    } else {
        const int batch = row0 >> 13;
        const int nqb = (row0 & 8191) + pair * 32;
#pragma unroll
        for (int nt = 0; nt < 4; ++nt) {
            const int n = h * 128 + nt * 32 + lm;
            const float bsv = bias[n];
            unsigned short* dst = v_emb_t + (size_t)batch * DH_ * NQ_ + (size_t)n * NQ_ + nqb;
#pragma unroll
            for (int g = 0; g < 4; ++g) {
                u16x4 pk;
#pragma unroll
                for (int j = 0; j < 4; ++j) pk[j] = f2h(acc[nt][4 * g + j] + bsv);
                *(u16x4*)(dst + 8 * g + 4 * lh) = pk;
            }
        }
    }
}

// ---------------------------------------------------------------------------
// Kernel 3: flash attention — producer/consumer wave specialization with a
// software pipeline across k-tiles.  NT_ = NK/BN = 128 tiles (R5 bug: loop
// was written for 64 tiles -> attended only half the keys).
// grid 256 (B*NQ/64), block 512 = 8 waves:
//   waves 0..3 (S):  role (kt = wv&1, pair_s = wv>>1): S^T tile i (32k x 32q),
//                    LOCAL-max softmax, write P + (pm,psum) stats.
//   waves 4..7 (PV): role (pair_v = pv&1, dh = pv>>1): consume tile i-1
//                    (P, stats, Vt), rescale O, accumulate; own all staging.
// Double-buffered kbuf/vbuf/pbuf/stats; 2 barriers/iter; NT_+1 skewed loop.
// Consumer applies exp(pm_kt - mn) as f16 scalar on pf (per-k-tile rescale).
// ---------------------------------------------------------------------------
#define BN_ 64
#define NT_ (NK_ / BN_)      // 128 tiles
#define KSTR 528   // 64 k-rows x (512+16)
#define VSTR 144   // 256 d-rows x (128+16)
#define PSTR 144   // 64 q-rows x (128+16)
#define KB_SZ (64 * KSTR)    // 33792
#define VB_SZ (256 * VSTR)   // 36864
#define PB_SZ (64 * PSTR)    // 9216
#define ST_SZ 1024           // 64 q x 4 floats (pm0,pm1,ps0,ps1)
#define LDS_TOTAL (2 * KB_SZ + 2 * VB_SZ + 2 * PB_SZ + 2 * ST_SZ)  // 161792

__global__ __launch_bounds__(512, 2) void flash(
    const unsigned short* __restrict__ q_emb, const unsigned short* __restrict__ k_emb,
    const unsigned short* __restrict__ v_emb_t, float* __restrict__ out) {
    __shared__ __align__(16) char lds[LDS_TOTAL];
    char* kbufs = lds;                              // 2 x [64][528]
    char* vbufs = lds + 2 * KB_SZ;                  // 2 x [256][144]
    char* pbufs = lds + 2 * KB_SZ + 2 * VB_SZ;      // 2 x [64][144]
    float* stats = (float*)(lds + 2 * KB_SZ + 2 * VB_SZ + 2 * PB_SZ);  // 2 x [64][4]

    const int tid = threadIdx.x;
    const int l = tid & 63, wv = tid >> 6;
    const int lm = l & 31, lh = l >> 5;
    const bool sWave = (wv < 4);
    const int kt = wv & 1, pair_s = (wv >> 1) & 1;        // S role
    const int pv = wv - 4, pair_v = pv & 1, dh = pv >> 1; // PV role

    const int bx = blockIdx.x;
    const int batch = bx >> 7;
    const int qb = (bx & 127) * 64;

    const unsigned short* kg = k_emb + (size_t)batch * NQ_ * 256;
    const unsigned short* vg = v_emb_t + (size_t)batch * DH_ * NQ_;

    // ---- S-wave persistent state: Q fragments ----
    f16x8 qf[16];
    if (sWave) {
        const int mrow = batch * NQ_ + qb + pair_s * 32 + lm;
#pragma unroll
        for (int ks = 0; ks < 16; ++ks)
            qf[ks] = *(const f16x8*)(q_emb + (size_t)mrow * 256 + ks * 16 + lh * 8);
    }

    // ---- PV-wave persistent state ----
    f32x16 oacc[4];
#pragma unroll
    for (int i = 0; i < 4; ++i)
#pragma unroll
        for (int j = 0; j < 16; ++j) oacc[i][j] = 0.0f;
    float mstat = -3.0e38f, lstat = 0.0f;

    // staging (PV waves only): 256 lanes
    const int pid = pv * 64 + l;               // 0..255
    const int krow = pid >> 2, ka = pid & 3;   // K: 64 rows x 4 lanes
    const int vrow = pid;                      // V: 1 d-row per lane
    u32x4 kreg[8], vreg[8];

    if (!sWave) {
        // prologue: tile 0 -> LDS slot 0; tile 1 -> regs
#pragma unroll
        for (int j = 0; j < 8; ++j)
            kreg[j] = *(const u32x4*)(kg + (size_t)krow * 256 + (ka + 4 * j) * 8);
#pragma unroll
        for (int j = 0; j < 8; ++j)
            vreg[j] = *(const u32x4*)(vg + (size_t)vrow * NQ_ + j * 8);
#pragma unroll
        for (int j = 0; j < 8; ++j)
            *(u32x4*)(kbufs + krow * KSTR + (ka + 4 * j) * 16) = kreg[j];
#pragma unroll
        for (int j = 0; j < 8; ++j)
            *(u32x4*)(vbufs + vrow * VSTR + j * 16) = vreg[j];
#pragma unroll
        for (int j = 0; j < 8; ++j)
            kreg[j] = *(const u32x4*)(kg + (size_t)(BN_ + krow) * 256 + (ka + 4 * j) * 8);
#pragma unroll
        for (int j = 0; j < 8; ++j)
            vreg[j] = *(const u32x4*)(vg + (size_t)vrow * NQ_ + BN_ + j * 8);
    }

    for (int i = 0; i <= NT_; ++i) {
        const int cur = i & 1, prv = cur ^ 1;
        __syncthreads();   // B1
        if (sWave) {
            if (i < NT_) {
                // ---- S^T tile i: A = K rows kt*32+lm, B = qf; 2 chains ----
                const char* kc = kbufs + cur * KB_SZ;
                f32x16 sa, sb;
#pragma unroll
                for (int j = 0; j < 16; ++j) { sa[j] = 0.0f; sb[j] = 0.0f; }
#pragma unroll
                for (int ks = 0; ks < 8; ++ks) {
                    f16x8 kf = *(const f16x8*)(kc + (kt * 32 + lm) * KSTR + ks * 32 + lh * 16);
                    sa = __builtin_amdgcn_mfma_f32_32x32x16_f16(kf, qf[ks], sa, 0, 0, 0);
                }
#pragma unroll
                for (int ks = 8; ks < 16; ++ks) {
                    f16x8 kf = *(const f16x8*)(kc + (kt * 32 + lm) * KSTR + ks * 32 + lh * 16);
                    sb = __builtin_amdgcn_mfma_f32_32x32x16_f16(kf, qf[ks], sb, 0, 0, 0);
                }
                f32x16 s = sa + sb;

                // local tile max (per lane q = lm over this tile's 32 k)
                float pm = s[0];
#pragma unroll
                for (int j = 1; j < 16; ++j) pm = fmaxf(pm, s[j]);
                pm = fmaxf(pm, __shfl_xor(pm, 32, 64));

                // exp vs LOCAL max; fp16-round before sum (num/denom consistent)
                float psum = 0.0f;
                char* pc = pbufs + cur * PB_SZ;
#pragma unroll
                for (int g = 0; g < 4; ++g) {
                    u16x4 pk;
#pragma unroll
                    for (int j = 0; j < 4; ++j) {
                        const unsigned short hh = f2h(__expf(s[g * 4 + j] - pm));
                        pk[j] = hh;
                        psum += h2f(hh);
                    }
                    *(u16x4*)(pc + (pair_s * 32 + lm) * PSTR + kt * 64 + g * 16 + lh * 8) = pk;
                }
                psum += __shfl_xor(psum, 32, 64);
                if (lh == 0) {
                    float* st = stats + cur * 256 + (pair_s * 32 + lm) * 4;
                    st[kt] = pm;
                    st[2 + kt] = psum;
                }
            }
        } else {
            if (i >= 1) {
                // ---- PV step for tile i-1 ----
                const float4 s4 = *(const float4*)(stats + prv * 256 + (pair_v * 32 + lm) * 4);
                const float mn = fmaxf(mstat, fmaxf(s4.x, s4.y));
                const float alpha = __expf(mstat - mn);
                const float sc0 = __expf(s4.x - mn);
                const float sc1 = __expf(s4.y - mn);
                mstat = mn;
                lstat = lstat * alpha + s4.z * sc0 + s4.w * sc1;
#pragma unroll
                for (int dt = 0; dt < 4; ++dt)
#pragma unroll
                    for (int j = 0; j < 16; ++j) oacc[dt][j] *= alpha;

                const _Float16 sch[2] = { (_Float16)sc0, (_Float16)sc1 };
                const char* pc = pbufs + prv * PB_SZ;
                const char* vc = vbufs + prv * VB_SZ;
#pragma unroll
                for (int ks2 = 0; ks2 < 4; ++ks2) {
                    f16x8 pf = *(const f16x8*)(pc + (pair_v * 32 + lm) * PSTR + ks2 * 32 + lh * 16);
                    pf = pf * sch[ks2 >> 1];
#pragma unroll
                    for (int dt = 0; dt < 4; ++dt) {
                        f16x8 vf = *(const f16x8*)(vc + (dh * 128 + dt * 32 + lm) * VSTR + ks2 * 32 + lh * 16);
                        oacc[dt] = __builtin_amdgcn_mfma_f32_32x32x16_f16(vf, pf, oacc[dt], 0, 0, 0);
                    }
                }
            }
            // ---- K tile i+1 -> LDS slot prv (after PV to hide load latency) ----
            if (i < NT_ - 1) {
#pragma unroll
                for (int j = 0; j < 8; ++j)
                    *(u32x4*)(kbufs + prv * KB_SZ + krow * KSTR + (ka + 4 * j) * 16) = kreg[j];
            }
        }
        __syncthreads();   // B2
        if (!sWave) {
            if (i < NT_ - 1) {
#pragma unroll
                for (int j = 0; j < 8; ++j)
                    *(u32x4*)(vbufs + prv * VB_SZ + vrow * VSTR + j * 16) = vreg[j];
            }
            if (i < NT_ - 2) {
                const int nkb = (i + 2) * BN_;
#pragma unroll
                for (int j = 0; j < 8; ++j)
                    kreg[j] = *(const u32x4*)(kg + (size_t)(nkb + krow) * 256 + (ka + 4 * j) * 8);
#pragma unroll
                for (int j = 0; j < 8; ++j)
                    vreg[j] = *(const u32x4*)(vg + (size_t)vrow * NQ_ + nkb + j * 8);
            }
        }
    }

    // ---- epilogue: PV waves hold all of O ----
    if (!sWave) {
        const float linv = 1.0f / lstat;
        float* orow = out + (size_t)(batch * NQ_ + qb + pair_v * 32 + lm) * 256;
#pragma unroll
        for (int dt = 0; dt < 4; ++dt) {
#pragma unroll
            for (int g = 0; g < 4; ++g) {
                float4 o4;
                o4.x = oacc[dt][4 * g + 0] * linv;
                o4.y = oacc[dt][4 * g + 1] * linv;
                o4.z = oacc[dt][4 * g + 2] * linv;
                o4.w = oacc[dt][4 * g + 3] * linv;
                *(float4*)(orow + dh * 128 + dt * 32 + 8 * g + 4 * lh) = o4;
            }
        }
    }
}

// ---------------------------------------------------------------------------
extern "C" void kernel_launch(void* const* d_in, const int* in_sizes, int n_in,
                              void* d_out, int out_size, void* d_ws, size_t ws_size,
                              hipStream_t stream) {
    const float* q  = (const float*)d_in[0];
    const float* k  = (const float*)d_in[1];
    const float* v  = (const float*)d_in[2];
    const float* Wq = (const float*)d_in[3];
    const float* bq = (const float*)d_in[4];
    const float* Wk = (const float*)d_in[5];
    const float* bk = (const float*)d_in[6];
    const float* Wv = (const float*)d_in[7];
    const float* bv = (const float*)d_in[8];
    float* out = (float*)d_out;

    unsigned short* wt      = (unsigned short*)d_ws;          // 3 * 256*256 fp16
    unsigned short* q_emb   = wt + 3 * 65536;                 // [16384][256]
    unsigned short* k_emb   = q_emb + (size_t)M_ * DH_;       // [16384][256]
    unsigned short* v_emb_t = k_emb + (size_t)M_ * DH_;       // [2][256][8192]

    wt_conv<<<dim3(4, 4, 3), 256, 0, stream>>>(Wq, Wk, Wv, wt);
    proj<<<dim3(256, 3), 256, 0, stream>>>(q, k, v, bq, bk, bv, wt, q_emb, k_emb, v_emb_t);
    flash<<<256, 512, 0, stream>>>(q_emb, k_emb, v_emb_t, out);
}

// Round 7
// 370.866 us; speedup vs baseline: 1.1023x; 1.1023x over previous
//
#include <hip/hip_runtime.h>

// Problem constants
#define B_   2
#define NQ_  8192
#define NK_  8192
#define DIN_ 256
#define DH_  256
#define M_   (B_ * NQ_)   // 16384 flattened rows

typedef _Float16 f16x8 __attribute__((ext_vector_type(8)));
typedef unsigned short u16x8 __attribute__((ext_vector_type(8)));
typedef unsigned short u16x4 __attribute__((ext_vector_type(4)));
typedef unsigned int  u32x4 __attribute__((ext_vector_type(4)));
typedef float f32x16 __attribute__((ext_vector_type(16)));

__device__ __forceinline__ unsigned short f2h(float f) {
    _Float16 h = (_Float16)f;
    return __builtin_bit_cast(unsigned short, h);
}
__device__ __forceinline__ float h2f(unsigned short u) {
    return (float)__builtin_bit_cast(_Float16, u);
}

// ---------------------------------------------------------------------------
// Kernel 1: weight convert + transpose via LDS tile (both sides coalesced).
// wt[mat][n][k] = fp16(W[mat][k][n]).  grid (4,4,3), block 256.
// ---------------------------------------------------------------------------
__global__ void wt_conv(const float* __restrict__ Wq, const float* __restrict__ Wk,
                        const float* __restrict__ Wv, unsigned short* __restrict__ wt) {
    __shared__ float tile[64][65];
    const int mat = blockIdx.z;
    const int k0 = blockIdx.x * 64, n0 = blockIdx.y * 64;
    const float* W = (mat == 0) ? Wq : (mat == 1) ? Wk : Wv;
#pragma unroll
    for (int p = 0; p < 16; ++p) {
        const int idx = p * 256 + threadIdx.x;
        const int r = idx >> 6, c = idx & 63;
        tile[r][c] = W[(k0 + r) * 256 + n0 + c];
    }
    __syncthreads();
#pragma unroll
    for (int p = 0; p < 16; ++p) {
        const int idx = p * 256 + threadIdx.x;
        const int nr = idx >> 6, kc = idx & 63;
        wt[mat * 65536 + (n0 + nr) * 256 + k0 + kc] = f2h(tile[kc][nr]);
    }
}

// ---------------------------------------------------------------------------
// Kernel 2: projections with 1-deep register prefetch on the X row chain.
// ---------------------------------------------------------------------------
__global__ __launch_bounds__(256) void proj(
    const float* __restrict__ xq, const float* __restrict__ xk, const float* __restrict__ xv,
    const float* __restrict__ bq, const float* __restrict__ bk, const float* __restrict__ bv,
    const unsigned short* __restrict__ wt,
    unsigned short* __restrict__ q_emb, unsigned short* __restrict__ k_emb,
    unsigned short* __restrict__ v_emb_t) {
    const int mat = blockIdx.y;
    const float* x    = (mat == 0) ? xq : (mat == 1) ? xk : xv;
    const float* bias = (mat == 0) ? bq : (mat == 1) ? bk : bv;
    const unsigned short* w = wt + mat * 65536;

    const int tid = threadIdx.x;
    const int l = tid & 63, wv = tid >> 6;
    const int pair = wv >> 1, h = wv & 1;
    const int lm = l & 31, lh = l >> 5;
    const int row0 = blockIdx.x * 64;
    const int m = row0 + pair * 32 + lm;

    f32x16 acc[4];
#pragma unroll
    for (int i = 0; i < 4; ++i)
#pragma unroll
        for (int j = 0; j < 16; ++j) acc[i][j] = 0.0f;

    const float4* xrow = (const float4*)(x + (size_t)m * 256 + lh * 8);
    float4 a0 = xrow[0], a1 = xrow[1];
#pragma unroll
    for (int ks = 0; ks < 16; ++ks) {
        float4 n0 = a0, n1 = a1;
        if (ks < 15) { n0 = xrow[(ks + 1) * 4]; n1 = xrow[(ks + 1) * 4 + 1]; }
        u16x8 au;
        au[0] = f2h(a0.x); au[1] = f2h(a0.y); au[2] = f2h(a0.z); au[3] = f2h(a0.w);
        au[4] = f2h(a1.x); au[5] = f2h(a1.y); au[6] = f2h(a1.z); au[7] = f2h(a1.w);
        f16x8 af = __builtin_bit_cast(f16x8, au);
#pragma unroll
        for (int nt = 0; nt < 4; ++nt) {
            f16x8 bfr = *(const f16x8*)(w + (h * 128 + nt * 32 + lm) * 256 + ks * 16 + lh * 8);
            acc[nt] = __builtin_amdgcn_mfma_f32_32x32x16_f16(af, bfr, acc[nt], 0, 0, 0);
        }
        a0 = n0; a1 = n1;
    }

    if (mat < 2) {
        unsigned short* emb = (mat == 0) ? q_emb : k_emb;
#pragma unroll
        for (int nt = 0; nt < 4; ++nt) {
            const int n = h * 128 + nt * 32 + lm;
            const float bsv = bias[n];
#pragma unroll
            for (int r = 0; r < 16; ++r) {
                const int rl = (r & 3) + 8 * (r >> 2) + 4 * lh;
                emb[(size_t)(row0 + pair * 32 + rl) * 256 + n] = f2h(acc[nt][r] + bsv);
            }
        }
    } else {
        const int batch = row0 >> 13;
        const int nqb = (row0 & 8191) + pair * 32;
#pragma unroll
        for (int nt = 0; nt < 4; ++nt) {
            const int n = h * 128 + nt * 32 + lm;
            const float bsv = bias[n];
            unsigned short* dst = v_emb_t + (size_t)batch * DH_ * NQ_ + (size_t)n * NQ_ + nqb;
#pragma unroll
            for (int g = 0; g < 4; ++g) {
                u16x4 pk;
#pragma unroll
                for (int j = 0; j < 4; ++j) pk[j] = f2h(acc[nt][4 * g + j] + bsv);
                *(u16x4*)(dst + 8 * g + 4 * lh) = pk;
            }
        }
    }
}

// ---------------------------------------------------------------------------
// Kernel 3: flash attention, kv-split x2, 2 blocks/CU.
// grid 512: bx&255 -> (batch, qb); bx>>8 -> key-range split (4096 keys each).
// block 256 = 4 waves, phase-locked (R4 structure, which beat specialization):
//   S phase:  wave -> (kt = wv>>1, pr = wv&1): one 32k x 32q S^T tile,
//             LOCAL-max softmax (R6-proven math), P + (pm,psum) stats write.
//   PV phase: wave -> dq = wv (64d quarter) x 64q; per-k-tile rescale
//             exp(pm_kt - mn) folded into pf as f16 scalar.
// LDS = 80896 B <= 81920 -> 2 blocks/CU: independent barrier domains overlap
// each other's barrier drains / staging latency.
// Output: UNNORMALIZED O partial + (m,l) per split; combine kernel merges.
// ---------------------------------------------------------------------------
#define BN_ 64
#define NSPLIT_ 2
#define KPS_ (NK_ / NSPLIT_)   // 4096 keys per split
#define NT_ (KPS_ / BN_)       // 64 iterations
#define KSTR 528   // 64 k-rows x (512+16): 33 granules, coprime 32
#define VSTR 144   // 256 d-rows x (128+16): 9 granules
#define PSTR 144   // 64 q-rows x (128+16)
#define KB_SZ (64 * KSTR)    // 33792
#define VB_SZ (256 * VSTR)   // 36864
#define PB_SZ (64 * PSTR)    // 9216
#define LDS_TOTAL (KB_SZ + VB_SZ + PB_SZ + 1024)   // 80896 <= 81920 (2/CU)

__global__ __launch_bounds__(256, 2) void flash(
    const unsigned short* __restrict__ q_emb, const unsigned short* __restrict__ k_emb,
    const unsigned short* __restrict__ v_emb_t,
    float* __restrict__ opart, float2* __restrict__ ml) {
    __shared__ __align__(16) char lds[LDS_TOTAL];
    char* kbuf = lds;                       // [64][528]
    char* vbuf = lds + KB_SZ;               // [256][144]
    char* pbuf = lds + KB_SZ + VB_SZ;       // [64][144]
    float* stats = (float*)(lds + KB_SZ + VB_SZ + PB_SZ);  // [64][4]: m0,m1,ps0,ps1

    const int tid = threadIdx.x;
    const int l = tid & 63, wv = tid >> 6;  // wv 0..3
    const int lm = l & 31, lh = l >> 5;
    const int kt = wv >> 1, pr = wv & 1;    // S role
    const int dq = wv;                      // PV role: d-quarter

    const int bx = blockIdx.x;
    const int qidx = bx & 255, split = bx >> 8;
    const int batch = qidx >> 7;
    const int qb = (qidx & 127) * 64;
    const int kb0 = split * KPS_;

    const unsigned short* kg = k_emb + (size_t)batch * NQ_ * 256;
    const unsigned short* vg = v_emb_t + (size_t)batch * DH_ * NQ_;

    // Q fragments register-resident for this wave's pr q-half.
    const int mrow = batch * NQ_ + qb + pr * 32 + lm;
    f16x8 qf[16];
#pragma unroll
    for (int ks = 0; ks < 16; ++ks)
        qf[ks] = *(const f16x8*)(q_emb + (size_t)mrow * 256 + ks * 16 + lh * 8);

    // O^T accumulator: [h*2+dt] = q-half h, d-tile dt within quarter dq.
    f32x16 oacc[4];
#pragma unroll
    for (int i = 0; i < 4; ++i)
#pragma unroll
        for (int j = 0; j < 16; ++j) oacc[i][j] = 0.0f;
    float mstat[2] = { -3.0e38f, -3.0e38f };
    float lstat[2] = { 0.0f, 0.0f };

    // staging: K 64 rows x 4 thr/row (8 x 16B each); V 256 rows x 1 thr/row.
    const int krow = tid >> 2, ka = tid & 3;
    const int vrow = tid;

    for (int i = 0; i < NT_; ++i) {
        const int kb = kb0 + i * BN_;
        __syncthreads();   // B1: prior iteration's LDS reads complete
#pragma unroll
        for (int j = 0; j < 8; ++j) {
            u32x4 val = *(const u32x4*)(kg + (size_t)(kb + krow) * 256 + (ka + 4 * j) * 8);
            *(u32x4*)(kbuf + krow * KSTR + (ka + 4 * j) * 16) = val;
        }
#pragma unroll
        for (int j = 0; j < 8; ++j) {
            u32x4 val = *(const u32x4*)(vg + (size_t)vrow * NQ_ + kb + j * 8);
            *(u32x4*)(vbuf + vrow * VSTR + j * 16) = val;
        }
        __syncthreads();   // B2: tiles visible

        // ---- S^T tile (kt, pr): A = K rows kt*32+lm, B = qf ----
        f32x16 s;
#pragma unroll
        for (int j = 0; j < 16; ++j) s[j] = 0.0f;
#pragma unroll
        for (int ks = 0; ks < 16; ++ks) {
            f16x8 kf = *(const f16x8*)(kbuf + (kt * 32 + lm) * KSTR + ks * 32 + lh * 16);
            s = __builtin_amdgcn_mfma_f32_32x32x16_f16(kf, qf[ks], s, 0, 0, 0);
        }

        // local tile max (per lane q = pr*32+lm over this tile's 32 k)
        float pm = s[0];
#pragma unroll
        for (int j = 1; j < 16; ++j) pm = fmaxf(pm, s[j]);
        pm = fmaxf(pm, __shfl_xor(pm, 32, 64));

        // exp vs LOCAL max; fp16-round before sum (num/denom consistent)
        float psum = 0.0f;
#pragma unroll
        for (int g = 0; g < 4; ++g) {
            u16x4 pk;
#pragma unroll
            for (int j = 0; j < 4; ++j) {
                const unsigned short hh = f2h(__expf(s[g * 4 + j] - pm));
                pk[j] = hh;
                psum += h2f(hh);
            }
            *(u16x4*)(pbuf + (pr * 32 + lm) * PSTR + kt * 64 + g * 16 + lh * 8) = pk;
        }
        psum += __shfl_xor(psum, 32, 64);
        if (lh == 0) {
            float* st = stats + (pr * 32 + lm) * 4;
            st[kt] = pm;
            st[2 + kt] = psum;
        }
        __syncthreads();   // B3: P + stats visible

        // ---- PV: this wave's d-quarter dq, both q-halves ----
#pragma unroll
        for (int h = 0; h < 2; ++h) {
            const float4 s4 = *(const float4*)&stats[(h * 32 + lm) * 4];
            const float mn = fmaxf(mstat[h], fmaxf(s4.x, s4.y));
            const float alpha = __expf(mstat[h] - mn);
            const float sc0 = __expf(s4.x - mn);
            const float sc1 = __expf(s4.y - mn);
            mstat[h] = mn;
            lstat[h] = lstat[h] * alpha + s4.z * sc0 + s4.w * sc1;
#pragma unroll
            for (int dt = 0; dt < 2; ++dt)
#pragma unroll
                for (int j = 0; j < 16; ++j) oacc[h * 2 + dt][j] *= alpha;

            const _Float16 sch[2] = { (_Float16)sc0, (_Float16)sc1 };
#pragma unroll
            for (int ks2 = 0; ks2 < 4; ++ks2) {
                f16x8 pf = *(const f16x8*)(pbuf + (h * 32 + lm) * PSTR + ks2 * 32 + lh * 16);
                pf = pf * sch[ks2 >> 1];
#pragma unroll
                for (int dt = 0; dt < 2; ++dt) {
                    f16x8 vf = *(const f16x8*)(vbuf + (dq * 64 + dt * 32 + lm) * VSTR + ks2 * 32 + lh * 16);
                    oacc[h * 2 + dt] = __builtin_amdgcn_mfma_f32_32x32x16_f16(vf, pf, oacc[h * 2 + dt], 0, 0, 0);
                }
            }
        }
    }

    // ---- epilogue: UNNORMALIZED partial O + (m,l) per split ----
#pragma unroll
    for (int h = 0; h < 2; ++h) {
        float* orow = opart + ((size_t)split * M_ + batch * NQ_ + qb + h * 32 + lm) * 256;
#pragma unroll
        for (int dt = 0; dt < 2; ++dt) {
#pragma unroll
            for (int g = 0; g < 4; ++g) {
                float4 o4;
                o4.x = oacc[h * 2 + dt][4 * g + 0];
                o4.y = oacc[h * 2 + dt][4 * g + 1];
                o4.z = oacc[h * 2 + dt][4 * g + 2];
                o4.w = oacc[h * 2 + dt][4 * g + 3];
                *(float4*)(orow + dq * 64 + dt * 32 + 8 * g + 4 * lh) = o4;
            }
        }
    }
    if (wv == 0 && lh == 0) {
#pragma unroll
        for (int h = 0; h < 2; ++h)
            ml[(size_t)split * M_ + batch * NQ_ + qb + h * 32 + lm] =
                make_float2(mstat[h], lstat[h]);
    }
}

// ---------------------------------------------------------------------------
// Kernel 4: combine the 2 kv-splits.  grid 4096, block 256; thread = 1 float4.
// out = (w0*O0 + w1*O1) / (w0*l0 + w1*l1), wX = exp(mX - max(m0,m1)).
// ---------------------------------------------------------------------------
__global__ void combine(const float* __restrict__ opart, const float2* __restrict__ ml,
                        float* __restrict__ out) {
    const int gid = blockIdx.x * 256 + threadIdx.x;   // 0 .. M_*64-1
    const int row = gid >> 6, c = gid & 63;
    const float2 a = ml[row];
    const float2 b = ml[M_ + row];
    const float mx = fmaxf(a.x, b.x);
    const float w0 = __expf(a.x - mx);
    const float w1 = __expf(b.x - mx);
    const float rinv = 1.0f / (w0 * a.y + w1 * b.y);
    const float4 o0 = ((const float4*)opart)[(size_t)row * 64 + c];
    const float4 o1 = ((const float4*)opart)[(size_t)M_ * 64 + (size_t)row * 64 + c];
    float4 o;
    o.x = (w0 * o0.x + w1 * o1.x) * rinv;
    o.y = (w0 * o0.y + w1 * o1.y) * rinv;
    o.z = (w0 * o0.z + w1 * o1.z) * rinv;
    o.w = (w0 * o0.w + w1 * o1.w) * rinv;
    ((float4*)out)[(size_t)row * 64 + c] = o;
}

// ---------------------------------------------------------------------------
extern "C" void kernel_launch(void* const* d_in, const int* in_sizes, int n_in,
                              void* d_out, int out_size, void* d_ws, size_t ws_size,
                              hipStream_t stream) {
    const float* q  = (const float*)d_in[0];
    const float* k  = (const float*)d_in[1];
    const float* v  = (const float*)d_in[2];
    const float* Wq = (const float*)d_in[3];
    const float* bq = (const float*)d_in[4];
    const float* Wk = (const float*)d_in[5];
    const float* bk = (const float*)d_in[6];
    const float* Wv = (const float*)d_in[7];
    const float* bv = (const float*)d_in[8];
    float* out = (float*)d_out;

    unsigned short* wt      = (unsigned short*)d_ws;          // 3*65536 fp16
    unsigned short* q_emb   = wt + 3 * 65536;                 // [16384][256]
    unsigned short* k_emb   = q_emb + (size_t)M_ * DH_;       // [16384][256]
    unsigned short* v_emb_t = k_emb + (size_t)M_ * DH_;       // [2][256][8192]
    // fp16 region ends at byte offset 25,559,040 (16B aligned)
    float*  opart = (float*)(v_emb_t + (size_t)M_ * DH_);     // [2][16384][256] fp32
    float2* ml    = (float2*)(opart + (size_t)2 * M_ * DH_);  // [2][16384]

    wt_conv<<<dim3(4, 4, 3), 256, 0, stream>>>(Wq, Wk, Wv, wt);
    proj<<<dim3(256, 3), 256, 0, stream>>>(q, k, v, bq, bk, bv, wt, q_emb, k_emb, v_emb_t);
    flash<<<512, 256, 0, stream>>>(q_emb, k_emb, v_emb_t, opart, ml);
    combine<<<4096, 256, 0, stream>>>(opart, ml, out);
}